// Round 13
// baseline (142.800 us; speedup 1.0000x reference)
//
#include <hip/hip_runtime.h>
#include <cstdint>
#include <cstddef>

// DigitCapsules routing: B=256, R=1152, C=10, IC=8, OC=16, 3 iters.
// R13 (4 launches) = R12 minus two reduce launches minus part1 fp32 traffic:
//   L1 caps_u_s1: u bf16 (94 MB) + fused pass-0 partial -> part1 PACKED BF16
//      (11.8 MB, was 23.6 fp32). Proven R11/R12 shape otherwise.
//   L2 caps_pass (pass1): PROLOGUE recomputes vsum1 = squash(0.1*sum part1)
//      per block (46 KB read, deterministic); main loop = R8's proven
//      NSPLIT=2 / 9-sweep shape; partials -> part2a.
//   L3 caps_pass (pass2): PROLOGUE = vsum1 (same part1 reduce) +
//      squash(sum part2a) added; main loop; partials -> part2b.
//   L4 caps_final: squash(sum part2b) -> out.
// Rationale: pass main loop is at a measured structural floor (~36 us,
// invariant across NSPLIT/width/burst shapes; u-read serve rate ~2.6 TB/s);
// remaining soft costs were 5 launch gaps (~17.6 us) + part1 round trips.
// Logits linear in v: b_t = u.(v1+..+v_{t-1}) -> running vsum, 1 pass/iter.
#define NB 256
#define NR 1152
#define NC 10
#define NI 8
#define NO 16
#define NSPLIT 2
#define NSWEEP 9     // r-sweeps per pass thread: 9*64 = 576 = NR/NSPLIT
#define NRC 144      // r-chunks in caps_u_s1 (8 r each)

static __device__ __forceinline__ uint32_t bf16_pack2(float lo, float hi) {
    uint32_t vl = __float_as_uint(lo);
    vl = vl + 0x7FFFu + ((vl >> 16) & 1u);
    uint32_t vh = __float_as_uint(hi);
    vh = vh + 0x7FFFu + ((vh >> 16) & 1u);
    return (vl >> 16) | (vh & 0xFFFF0000u);
}

// -------------------------------------------------------------------------
// caps_u_s1: 2304 blocks = 144 rc x 16 bg; 320 thr = c*32 + rl*4 + oq.
// W[r][c][i][oq*4..+3] = 8 float4 in regs; 16-deep b-loop.
// Per bi: u quad -> bf16 u-store + rl-shuffle-reduce (xor 4,8,16); rl==0
// lanes store PACKED-BF16 s1 partial (uint2) to part1[b][rc][c*8+oq*2].
__global__ __launch_bounds__(320, 2) void caps_u_s1_kernel(
    const float* __restrict__ x, const float* __restrict__ W,
    uint32_t* __restrict__ u, uint32_t* __restrict__ part1)
{
    const int t  = threadIdx.x;
    const int c  = t >> 5;             // 0..9
    const int rl = (t & 31) >> 2;      // 0..7
    const int oq = t & 3;              // 0..3
    const int rc = blockIdx.x >> 4;    // 0..143
    const int bg = blockIdx.x & 15;    // 0..15
    const int b0 = bg * 16;
    const int r  = rc * 8 + rl;

    __shared__ float xs[16][8][8];     // 4 KB

    if (t < 256) {                     // 256 float4 = x[b0..+16)[rc*8..+8)[8]
        const int bi = t >> 4, rem = t & 15;
        const int rr = rem >> 1, hf = rem & 1;
        *(float4*)&xs[bi][rr][hf * 4] =
            *(const float4*)(x + ((size_t)(b0 + bi) * NR + rc * 8 + rr) * 8 + hf * 4);
    }

    const float* wb = W + ((size_t)r * NC + c) * (NI * NO) + oq * 4;
    float4 wf[8];
#pragma unroll
    for (int i = 0; i < 8; ++i) wf[i] = *(const float4*)(wb + i * NO);

    __syncthreads();

#pragma unroll 2
    for (int bi = 0; bi < 16; ++bi) {
        const float4 xv4a = *(const float4*)&xs[bi][rl][0];
        const float4 xv4b = *(const float4*)&xs[bi][rl][4];
        const float xr[8] = {xv4a.x, xv4a.y, xv4a.z, xv4a.w,
                             xv4b.x, xv4b.y, xv4b.z, xv4b.w};
        float ax = 0.f, ay = 0.f, az = 0.f, aw = 0.f;
#pragma unroll
        for (int i = 0; i < 8; ++i) {
            const float xv = xr[i];
            ax = fmaf(xv, wf[i].x, ax); ay = fmaf(xv, wf[i].y, ay);
            az = fmaf(xv, wf[i].z, az); aw = fmaf(xv, wf[i].w, aw);
        }
        uint2 s;
        s.x = bf16_pack2(ax, ay);
        s.y = bf16_pack2(az, aw);
        *(uint2*)(u + (((size_t)(b0 + bi) * NC + c) * NR + r) * 8 + oq * 2) = s;

        // fused s1 partial: reduce fp32 quad over rl (lane bits 2..4)
        float sx = ax, sy = ay, sz = az, sw = aw;
#pragma unroll
        for (int off = 4; off <= 16; off <<= 1) {
            sx += __shfl_xor(sx, off); sy += __shfl_xor(sy, off);
            sz += __shfl_xor(sz, off); sw += __shfl_xor(sw, off);
        }
        if ((t & 28) == 0) {   // rl == 0 lanes: one uint2 per (bi,c,oq)
            uint2 p;
            p.x = bf16_pack2(sx, sy);
            p.y = bf16_pack2(sz, sw);
            *(uint2*)(part1 + ((size_t)(b0 + bi) * NRC + rc) * 80
                      + c * 8 + oq * 2) = p;
        }
    }
}

// -------------------------------------------------------------------------
// prologue helper: lanes t<160 (t = c*16 + o) compute vsum1[t] =
// squash(0.1 * sum over 144 rc of part1 bf16). Deterministic (index order).
static __device__ __forceinline__ float vsum1_col(
    const uint32_t* __restrict__ part1, const int b, const int t)
{
    const uint32_t* p = part1 + (size_t)b * NRC * 80 + (t >> 1);
    const bool hi = t & 1;
    float s0 = 0.f, s1 = 0.f, s2 = 0.f, s3 = 0.f;
#pragma unroll 4
    for (int g = 0; g < NRC; g += 4) {
        const uint32_t w0 = p[(g + 0) * 80];
        const uint32_t w1 = p[(g + 1) * 80];
        const uint32_t w2 = p[(g + 2) * 80];
        const uint32_t w3 = p[(g + 3) * 80];
        s0 += hi ? __uint_as_float(w0 & 0xFFFF0000u) : __uint_as_float(w0 << 16);
        s1 += hi ? __uint_as_float(w1 & 0xFFFF0000u) : __uint_as_float(w1 << 16);
        s2 += hi ? __uint_as_float(w2 & 0xFFFF0000u) : __uint_as_float(w2 << 16);
        s3 += hi ? __uint_as_float(w3 & 0xFFFF0000u) : __uint_as_float(w3 << 16);
    }
    const float s = 0.1f * ((s0 + s1) + (s2 + s3));
    float n2 = s * s;                 // squash over the 16 o-lanes of this c
    n2 += __shfl_xor(n2, 1);
    n2 += __shfl_xor(n2, 2);
    n2 += __shfl_xor(n2, 4);
    n2 += __shfl_xor(n2, 8);
    const float nrm   = sqrtf(n2);
    return s * (n2 / (1.f + n2) / (nrm + 1e-8f));
}

// -------------------------------------------------------------------------
// Routing pass (R8/R12's proven main loop): block = (b, sp), 256 thr =
// 64 rl x 4 oq, NSWEEP=9 sweeps of uint2 loads. cc = softmax_c(u.vss).
// Prologue builds vss in LDS: phase 1 -> vsum1 from part1;
// phase 2 -> vsum1 + squash(sum part2a). Partial s -> partout[sp][b][160].
__global__ __launch_bounds__(256, 2) void caps_pass_kernel(
    const uint32_t* __restrict__ u, const uint32_t* __restrict__ part1,
    const float* __restrict__ part_prev, float* __restrict__ partout)
{
    const int b  = blockIdx.x >> 1;
    const int sp = blockIdx.x & 1;
    const int t  = threadIdx.x;
    const int oq = t & 3;
    const int rl = t >> 2;    // 0..63

    __shared__ float vss[160];
    __shared__ float sred[4][160];

    if (t < 160) {
        float v = vsum1_col(part1, b, t);
        if (part_prev != nullptr) {       // phase 2: add squash(s2)
            const float s = part_prev[(size_t)b * 160 + t]
                          + part_prev[((size_t)NB + b) * 160 + t];
            float n2 = s * s;
            n2 += __shfl_xor(n2, 1);
            n2 += __shfl_xor(n2, 2);
            n2 += __shfl_xor(n2, 4);
            n2 += __shfl_xor(n2, 8);
            const float nrm = sqrtf(n2);
            v += s * (n2 / (1.f + n2) / (nrm + 1e-8f));
        }
        vss[t] = v;
    }
    __syncthreads();

    float acc[10][4];
#pragma unroll
    for (int c = 0; c < 10; ++c)
#pragma unroll
        for (int j = 0; j < 4; ++j) acc[c][j] = 0.f;

    const uint2* ub = (const uint2*)u + (size_t)b * NC * NR * 4 + oq;

    for (int k = 0; k < NSWEEP; ++k) {
        const int r = sp * (NSWEEP * 64) + k * 64 + rl;
        uint2 q[10];
#pragma unroll
        for (int c = 0; c < 10; ++c) q[c] = ub[((size_t)c * NR + r) * 4];

        float lg[10];
#pragma unroll
        for (int c = 0; c < 10; ++c) {
            const float4 vq = *(const float4*)&vss[c * 16 + oq * 4];
            float d = __uint_as_float(q[c].x << 16) * vq.x;
            d = fmaf(__uint_as_float(q[c].x & 0xFFFF0000u), vq.y, d);
            d = fmaf(__uint_as_float(q[c].y << 16),         vq.z, d);
            d = fmaf(__uint_as_float(q[c].y & 0xFFFF0000u), vq.w, d);
            lg[c] = d;
        }
#pragma unroll
        for (int c = 0; c < 10; ++c) {    // finish o-dot over 4 oq lanes
            lg[c] += __shfl_xor(lg[c], 1);
            lg[c] += __shfl_xor(lg[c], 2);
        }
        float m = lg[0];
#pragma unroll
        for (int c = 1; c < 10; ++c) m = fmaxf(m, lg[c]);
        float wgt[10], ssum = 0.f;
#pragma unroll
        for (int c = 0; c < 10; ++c) { wgt[c] = __expf(lg[c] - m); ssum += wgt[c]; }
        const float inv = 1.f / ssum;
#pragma unroll
        for (int c = 0; c < 10; ++c) {
            const float wv = wgt[c] * inv;
            acc[c][0] = fmaf(wv, __uint_as_float(q[c].x << 16),         acc[c][0]);
            acc[c][1] = fmaf(wv, __uint_as_float(q[c].x & 0xFFFF0000u), acc[c][1]);
            acc[c][2] = fmaf(wv, __uint_as_float(q[c].y << 16),         acc[c][2]);
            acc[c][3] = fmaf(wv, __uint_as_float(q[c].y & 0xFFFF0000u), acc[c][3]);
        }
    }

    // in-wave reduce over 16 rl-lanes (tid bits 2..5) — once per 9 r
#pragma unroll
    for (int off = 4; off <= 32; off <<= 1)
#pragma unroll
        for (int c = 0; c < 10; ++c)
#pragma unroll
            for (int j = 0; j < 4; ++j) acc[c][j] += __shfl_xor(acc[c][j], off);

    const int wv = t >> 6;
    if ((t & 63) < 4) {
#pragma unroll
        for (int c = 0; c < 10; ++c)
#pragma unroll
            for (int j = 0; j < 4; ++j)
                sred[wv][c * 16 + oq * 4 + j] = acc[c][j];
    }
    __syncthreads();

    if (t < 160) {
        partout[((size_t)sp * NB + b) * 160 + t]
            = sred[0][t] + sred[1][t] + sred[2][t] + sred[3][t];
    }
}

// -------------------------------------------------------------------------
// final: out = squash(sum part2b). grid=256 (b), 192 thr (160 active).
__global__ __launch_bounds__(192) void caps_final_kernel(
    const float* __restrict__ part2b, float* __restrict__ out)
{
    const int b = blockIdx.x;
    const int t = threadIdx.x;
    if (t >= 160) return;
    const float s = part2b[(size_t)b * 160 + t]
                  + part2b[((size_t)NB + b) * 160 + t];
    float n2 = s * s;
    n2 += __shfl_xor(n2, 1);
    n2 += __shfl_xor(n2, 2);
    n2 += __shfl_xor(n2, 4);
    n2 += __shfl_xor(n2, 8);
    const float nrm   = sqrtf(n2);
    const float scale = n2 / (1.f + n2) / (nrm + 1e-8f);
    out[(size_t)b * 160 + t] = scale * s;
}

// -------------------------------------------------------------------------
extern "C" void kernel_launch(void* const* d_in, const int* in_sizes, int n_in,
                              void* d_out, int out_size, void* d_ws, size_t ws_size,
                              hipStream_t stream) {
    const float* x = (const float*)d_in[0];   // [256,1152,8]
    const float* W = (const float*)d_in[1];   // [1,1152,10,8,16]
    float* out = (float*)d_out;               // [256,10,16]

    // ws: u 94,371,840 | part1 bf16 [256][144][80 u32] = 11,796,480
    //     part2a 2*256*160*4 = 327,680 | part2b 327,680
    uint8_t*  ws   = (uint8_t*)d_ws;
    uint32_t* u    = (uint32_t*)ws;
    uint32_t* prt1 = (uint32_t*)(ws + 94371840u);
    float*    p2a  = (float*)(ws + 94371840u + 11796480u);
    float*    p2b  = (float*)(ws + 94371840u + 11796480u + 327680u);

    caps_u_s1_kernel<<<2304, 320, 0, stream>>>(x, W, u, prt1);
    caps_pass_kernel<<<NB * NSPLIT, 256, 0, stream>>>(u, prt1, nullptr, p2a);
    caps_pass_kernel<<<NB * NSPLIT, 256, 0, stream>>>(u, prt1, p2a, p2b);
    caps_final_kernel<<<NB, 192, 0, stream>>>(p2b, out);
}